// Round 1
// baseline (74.605 us; speedup 1.0000x reference)
//
#include <hip/hip_runtime.h>

// CenterLoss: scalar = 0.003 * ( sum_b clamp(||e_b - c_{l_b}||^2, 1e-12, 1e12)
//                                + B*(C-1)*1e-12 ) / B
// B=4096, D=512, C=10000, all fp32; labels int.

#define LAMBDA_C  0.003f
#define CLAMP_MIN 1e-12f
#define CLAMP_MAX 1e12f

static constexpr int B = 4096;
static constexpr int D = 512;
static constexpr int C = 10000;

// One 64-lane wave per row; 4 waves (256 threads) per block; 1024 blocks.
// Lane i reads float4 at [lane + k*64] -> consecutive lanes hit consecutive
// 16B, fully coalesced (1 KiB per wave per load instruction).
__global__ __launch_bounds__(256) void row_dist_kernel(
    const float* __restrict__ emb,
    const int*   __restrict__ labels,
    const float* __restrict__ centers,
    float*       __restrict__ row_out)
{
    const int wave = threadIdx.x >> 6;          // 0..3
    const int lane = threadIdx.x & 63;
    const int row  = (blockIdx.x << 2) + wave;  // 0..4095

    const int label = labels[row];
    const float4* e4 = (const float4*)(emb     + (size_t)row   * D);
    const float4* c4 = (const float4*)(centers + (size_t)label * D);

    // D=512 -> 128 float4 per row; 64 lanes x 2 float4 each.
    float s = 0.0f;
#pragma unroll
    for (int k = 0; k < 2; ++k) {
        const float4 e = e4[lane + (k << 6)];
        const float4 c = c4[lane + (k << 6)];
        const float dx = e.x - c.x;
        const float dy = e.y - c.y;
        const float dz = e.z - c.z;
        const float dw = e.w - c.w;
        s += dx * dx + dy * dy + dz * dz + dw * dw;
    }

    // 64-lane wave reduction
#pragma unroll
    for (int off = 32; off > 0; off >>= 1)
        s += __shfl_down(s, off, 64);

    if (lane == 0) {
        s = fminf(fmaxf(s, CLAMP_MIN), CLAMP_MAX);
        row_out[row] = s;
    }
}

// Single-block reduction of the 4096 row distances -> scalar.
__global__ __launch_bounds__(256) void reduce_kernel(
    const float* __restrict__ row_in,
    float*       __restrict__ out)
{
    const float4* in4 = (const float4*)row_in;  // 1024 float4
    const int tid = threadIdx.x;

    float s = 0.0f;
#pragma unroll
    for (int i = 0; i < 4; ++i) {
        const float4 v = in4[tid + (i << 8)];
        s += v.x + v.y + v.z + v.w;
    }

#pragma unroll
    for (int off = 32; off > 0; off >>= 1)
        s += __shfl_down(s, off, 64);

    __shared__ float wsum[4];
    if ((tid & 63) == 0) wsum[tid >> 6] = s;
    __syncthreads();

    if (tid == 0) {
        const float total = wsum[0] + wsum[1] + wsum[2] + wsum[3];
        const float masked_floor = (float)B * (float)(C - 1) * CLAMP_MIN;
        out[0] = LAMBDA_C * ((total + masked_floor) / (float)B);
    }
}

extern "C" void kernel_launch(void* const* d_in, const int* in_sizes, int n_in,
                              void* d_out, int out_size, void* d_ws, size_t ws_size,
                              hipStream_t stream)
{
    const float* emb     = (const float*)d_in[0];   // [B, D] fp32
    const int*   labels  = (const int*)  d_in[1];   // [B] int
    const float* centers = (const float*)d_in[2];   // [C, D] fp32
    float*       out     = (float*)d_out;           // [1] fp32
    float*       row_buf = (float*)d_ws;            // B floats of scratch

    row_dist_kernel<<<B / 4, 256, 0, stream>>>(emb, labels, centers, row_buf);
    reduce_kernel<<<1, 256, 0, stream>>>(row_buf, out);
}